// Round 2
// baseline (12160.061 us; speedup 1.0000x reference)
//
#include <hip/hip_runtime.h>
#include <math.h>

#define NN     16384
#define DD     256
#define HH     1024
#define NROOTS 64
#define OUTST  96          // 32 trunk + 64 roots
#define TENC   33          // 32 trunk encoders + 1 output encoder
#define MAXL   256
#define NBINS  (MAXL*TENC) // 8448
#define GCAP   4096
#define RSLOTS 64          // ring of 64 group-slots

// ---- workspace byte offsets (ws[0..7] = hdr) ----
#define OFF_H     256u
#define OFF_YP    (OFF_H    + (unsigned)RSLOTS*16*HH*4u)  // h ring (4MB)
#define OFF_ORD   (OFF_YP   + (unsigned)RSLOTS*16*HH*4u)  // y-partial ring (4MB)
#define OFF_META  (OFF_ORD  + (unsigned)NN*4u)
#define OFF_HC    (OFF_META + (unsigned)GCAP*8u)
#define OFF_BC    (OFF_HC   + (unsigned)GCAP*4u)
#define OFF_NC    (OFF_BC   + (unsigned)GCAP*4u)
#define OFF_FREE  (OFF_NC   + (unsigned)GCAP*4u)
#define OFF_DONE  (OFF_FREE + 256u)
#define OFF_LVL   (OFF_DONE + (unsigned)NN*4u)
// end ~ 8.6 MB

__device__ __forceinline__ int ldrlx(int* p) {
  return __hip_atomic_load(p, __ATOMIC_RELAXED, __HIP_MEMORY_SCOPE_AGENT);
}
__device__ __forceinline__ void strel(int* p, int v) {
  __hip_atomic_store(p, v, __ATOMIC_RELEASE, __HIP_MEMORY_SCOPE_AGENT);
}
__device__ __forceinline__ void addrel(int* p) {
  __hip_atomic_fetch_add(p, 1, __ATOMIC_RELEASE, __HIP_MEMORY_SCOPE_AGENT);
}
__device__ __forceinline__ void acqfence() {
  __builtin_amdgcn_fence(__ATOMIC_ACQUIRE, "agent");
}
__device__ __forceinline__ void spin_ge(int* p, int target) {
  int it = 0;
  while (ldrlx(p) < target) {
    __builtin_amdgcn_s_sleep(8);
    if (++it > 4000000) break;   // hang fuse
  }
  acqfence();
}

// =============== kernel 1a: levels + inits + roots ===============
__global__ __launch_bounds__(1024) void k_sched_a(
    const int* __restrict__ nin, const float* __restrict__ root,
    char* __restrict__ ws, float* __restrict__ out)
{
  __shared__ unsigned short lvl[NN];
  __shared__ int flag;
  int tid = threadIdx.x;
  for (int n = tid; n < NN; n += 1024) lvl[n] = 0;
  __syncthreads();
  for (int c = 0; c < 16; ++c) {
    int n = (c << 10) + tid;
    int p0 = nin[2*n], p1 = nin[2*n+1];
    bool live = (n >= NROOTS);
    while (true) {
      if (tid == 0) flag = 0;
      __syncthreads();
      if (live) {
        int nl = 1 + max((int)lvl[p0], (int)lvl[p1]);
        if (nl > (int)lvl[n]) { lvl[n] = (unsigned short)nl; flag = 1; }
      }
      __syncthreads();
      int f = flag;
      __syncthreads();
      if (!f) break;
    }
  }
  unsigned short* lvlg = (unsigned short*)(ws + OFF_LVL);
  int* done = (int*)(ws + OFF_DONE);
  for (int n = tid; n < NN; n += 1024) { lvlg[n] = lvl[n]; done[n] = (n < NROOTS) ? 1 : 0; }
  int* hc = (int*)(ws + OFF_HC); int* bc = (int*)(ws + OFF_BC); int* nc = (int*)(ws + OFF_NC);
  for (int i = tid; i < GCAP; i += 1024) { hc[i] = 0; bc[i] = 0; nc[i] = 0; }
  int* fr = (int*)(ws + OFF_FREE);
  if (tid < RSLOTS) fr[tid] = 0;
  // roots: copy fp32 root embeddings straight into the output buffer
  for (int i = tid; i < NROOTS*DD; i += 1024) out[i] = root[i];
}

// =============== kernel 1b: counting sort by (level,type) + group metadata ===============
__global__ __launch_bounds__(1024) void k_sched_b(
    const int* __restrict__ nty, char* __restrict__ ws)
{
  __shared__ int hist[NBINS];
  __shared__ int wsum[16], wsum2[16];
  const unsigned short* lvl = (const unsigned short*)(ws + OFF_LVL);
  int*  order = (int*)(ws + OFF_ORD);
  int2* meta  = (int2*)(ws + OFF_META);
  int*  hdr   = (int*)ws;
  int tid = threadIdx.x;
  for (int i = tid; i < NBINS; i += 1024) hist[i] = 0;
  __syncthreads();
  for (int n = NROOTS + tid; n < NN; n += 1024) {
    int ty = nty[n];
    int pi = (ty >= OUTST) ? 32 : ty;
    int key = min((int)lvl[n] - 1, MAXL - 1) * TENC + pi;
    atomicAdd(&hist[key], 1);
  }
  __syncthreads();
  int base = tid * 9;
  int v[9]; int s = 0, gs = 0;
  #pragma unroll
  for (int j = 0; j < 9; ++j) {
    int idx = base + j;
    int cv = (idx < NBINS) ? hist[idx] : 0;
    v[j] = cv; s += cv; gs += (cv + 15) >> 4;
  }
  int lane = tid & 63, wid = tid >> 6;
  int xs = s, xg = gs;
  for (int off = 1; off < 64; off <<= 1) {
    int ys = __shfl_up(xs, off); int yg = __shfl_up(xg, off);
    if (lane >= off) { xs += ys; xg += yg; }
  }
  if (lane == 63) { wsum[wid] = xs; wsum2[wid] = xg; }
  __syncthreads();
  if (tid == 0) {
    int a = 0, b = 0;
    for (int w = 0; w < 16; ++w) {
      int t1 = wsum[w];  wsum[w]  = a; a += t1;
      int t2 = wsum2[w]; wsum2[w] = b; b += t2;
    }
    hdr[0] = b;            // num groups
    hdr[1] = b * 36;       // total tasks
  }
  __syncthreads();
  int run  = (xs - s)  + wsum[wid];
  int grun = (xg - gs) + wsum2[wid];
  #pragma unroll
  for (int j = 0; j < 9; ++j) {
    int idx = base + j;
    if (idx < NBINS) {
      int cv = v[j];
      int pi = idx % TENC;
      hist[idx] = run;  // becomes running scatter offset
      int ng = (cv + 15) >> 4;
      for (int sg = 0; sg < ng; ++sg) {
        int m = min(16, cv - 16*sg);
        meta[grun + sg] = make_int2(run + 16*sg, m | (pi << 8));
      }
      run += cv; grun += ng;
    }
  }
  __syncthreads();
  for (int n = NROOTS + tid; n < NN; n += 1024) {
    int ty = nty[n];
    int pi = (ty >= OUTST) ? 32 : ty;
    int key = min((int)lvl[n] - 1, MAXL - 1) * TENC + pi;
    int pos = atomicAdd(&hist[key], 1);
    order[pos] = n;
  }
}

// =============== fp32 batched-GEMV inner loop ===============
template<int MB>
__device__ __forceinline__ void gemv256(float (&acc)[16], const char* __restrict__ xb,
                                        const unsigned (&xo)[16],
                                        const float* __restrict__ wp, const int wstride)
{
  #pragma unroll 2
  for (int kq = 0; kq < 64; ++kq) {
    const float* w = wp + (kq * 4) * wstride;
    float w0 = w[0], w1 = w[wstride], w2 = w[2*wstride], w3 = w[3*wstride];
    unsigned kb = (unsigned)kq * 16u;
    #pragma unroll
    for (int mb = 0; mb < MB; ++mb) {
      #pragma unroll
      for (int mi = 0; mi < 4; ++mi) {
        const int m = mb*4 + mi;
        float4 x = *(const float4*)(xb + (xo[m] + kb));
        acc[m] = fmaf(x.x, w0, acc[m]);
        acc[m] = fmaf(x.y, w1, acc[m]);
        acc[m] = fmaf(x.z, w2, acc[m]);
        acc[m] = fmaf(x.w, w3, acc[m]);
      }
    }
  }
}
#define GEMV_SWITCH(MB, XB, XO, WP, WS)                     \
  switch (MB) {                                             \
    case 1: gemv256<1>(acc, XB, XO, WP, WS); break;         \
    case 2: gemv256<2>(acc, XB, XO, WP, WS); break;         \
    case 3: gemv256<3>(acc, XB, XO, WP, WS); break;         \
    default: gemv256<4>(acc, XB, XO, WP, WS); break;        \
  }

// =============== kernel 2: persistent event-driven DAG executor ===============
// 36 tasks per 16-node group g (global topological order):
//   sub 0..15 : A — layer1 64-col tile, K=512, writes h ring
//   sub 16..31: B — layer2 (ct,kc) tile, K=256 partial, writes y-partial ring
//   sub 32..35: N — combine + normalize, write fp32 row to out, done flags
__global__ __launch_bounds__(64, 4) void k_dag(
    const int* __restrict__ nin, const int* __restrict__ nty,
    const float* __restrict__ slot,
    const float* __restrict__ W1, const float* __restrict__ b1,
    const float* __restrict__ W2, const float* __restrict__ b2,
    char* __restrict__ ws, float* __restrict__ out, int G)
{
  int*   hdr   = (int*)ws;
  float* hring = (float*)(ws + OFF_H);
  float* ypart = (float*)(ws + OFF_YP);
  const int*  order = (const int*)(ws + OFF_ORD);
  const int2* meta  = (const int2*)(ws + OFF_META);
  int* hcnt = (int*)(ws + OFF_HC);
  int* bcnt = (int*)(ws + OFF_BC);
  int* ncnt = (int*)(ws + OFF_NC);
  int* freec = (int*)(ws + OFF_FREE);
  int* done = (int*)(ws + OFF_DONE);

  const int total = hdr[1];
  const int lane = threadIdx.x;

  for (int t = blockIdx.x; t < total; t += G) {
    int g = t / 36;
    int sub = t - g * 36;
    int2 mt = meta[g];
    int pos0 = mt.x;
    int M    = mt.y & 0xff;
    int pidx = mt.y >> 8;
    int slotr = g & (RSLOTS - 1);

    if (sub < 16) {
      // ---------------- A: layer 1 ----------------
      if ((g >> 6) > 0) spin_ge(&freec[slotr], g >> 6);   // ring slot free
      int p0my = 0, p1my = 0, tymy = 0;
      if (lane < M) {
        int nmy = order[pos0 + lane];
        p0my = nin[2*nmy]; p1my = nin[2*nmy + 1]; tymy = nty[nmy];
      }
      // parent readiness poll: lanes 0..M-1 wait p0, lanes 16..16+M-1 wait p1
      int pw = -1;
      if (lane < M) pw = p0my;
      int pp1 = __shfl(p1my, (lane >= 16) ? (lane - 16) : lane);
      if (pidx != 32 && lane >= 16 && lane < 32 && (lane - 16) < M) pw = pp1;
      {
        bool need = (pw >= 0);
        int it = 0;
        while (true) {
          int ok = need ? (ldrlx(&done[pw]) != 0) : 1;
          if (__all(ok)) break;
          __builtin_amdgcn_s_sleep(8);
          if (++it > 4000000) break;
        }
        acqfence();
      }
      int c = (sub << 6) + lane;
      float bias = b1[pidx * HH + c];
      float acc[16];
      #pragma unroll
      for (int m = 0; m < 16; ++m) acc[m] = bias;
      const float* wpa = W1 + (size_t)pidx * (2*DD) * HH + c;
      int MB = (M + 3) >> 2;
      // half 0: k=0..255 from parent-0 rows of out
      {
        unsigned xo0[16];
        #pragma unroll
        for (int m = 0; m < 16; ++m) {
          int mm = min(m, M - 1);
          xo0[m] = (unsigned)__shfl(p0my, mm) * (DD * 4u);
        }
        GEMV_SWITCH(MB, (const char*)out, xo0, wpa, HH);
      }
      // half 1: k=256..511 from parent-1 rows (or output_slot_emb rows)
      {
        const char* e1b = (pidx == 32) ? (const char*)slot : (const char*)out;
        unsigned xo1[16];
        #pragma unroll
        for (int m = 0; m < 16; ++m) {
          int mm = min(m, M - 1);
          int e1i = (pidx == 32) ? (__shfl(tymy, mm) - OUTST) : __shfl(p1my, mm);
          xo1[m] = (unsigned)e1i * (DD * 4u);
        }
        GEMV_SWITCH(MB, e1b, xo1, wpa + 256 * HH, HH);
      }
      // exact GELU + store h
      float* hrow = hring + (size_t)(slotr * 16) * HH + c;
      #pragma unroll
      for (int m = 0; m < 16; ++m) {
        if (m < M) {
          float u = acc[m];
          hrow[m * HH] = 0.5f * u * (1.0f + erff(u * 0.70710678118654752f));
        }
      }
      if (lane == 0) addrel(&hcnt[g]);

    } else if (sub < 32) {
      // ---------------- B: layer 2 (partial over K) ----------------
      int s2 = sub - 16;
      int ct = s2 >> 2, kc = s2 & 3;
      spin_ge(&hcnt[g], 16);
      int c = ct * 64 + lane;
      float acc[16];
      #pragma unroll
      for (int m = 0; m < 16; ++m) acc[m] = 0.0f;
      unsigned ho[16];
      #pragma unroll
      for (int m = 0; m < 16; ++m)
        ho[m] = (unsigned)(slotr * 16 + min(m, M - 1)) * (HH * 4u);
      const char* hb = (const char*)hring + (unsigned)kc * 1024u;  // + kc*256 floats
      const float* wpb = W2 + ((size_t)pidx * HH + kc * 256) * DD + c;
      int MB = (M + 3) >> 2;
      GEMV_SWITCH(MB, hb, ho, wpb, DD);
      #pragma unroll
      for (int m = 0; m < 16; ++m)
        if (m < M)
          ypart[(size_t)(slotr * 16 + m) * 1024 + kc * 256 + c] = acc[m];
      if (lane == 0) addrel(&bcnt[g]);

    } else {
      // ---------------- N: combine + normalize + write fp32 ----------------
      int mq = sub - 32;
      spin_ge(&bcnt[g], 16);
      int nlm = (lane < M) ? order[pos0 + lane] : 0;
      for (int mi = 0; mi < 4; ++mi) {
        int m = mq * 4 + mi;
        if (m >= M) break;
        int n = __shfl(nlm, m);
        const float4* yp = (const float4*)((const char*)ypart + (size_t)(slotr * 16 + m) * 4096);
        const float4* b2v = (const float4*)(b2 + pidx * DD);
        float4 y = b2v[lane];
        #pragma unroll
        for (int kc2 = 0; kc2 < 4; ++kc2) {
          float4 pv = yp[kc2 * 64 + lane];
          y.x += pv.x; y.y += pv.y; y.z += pv.z; y.w += pv.w;
        }
        float ssq = y.x*y.x + y.y*y.y + y.z*y.z + y.w*y.w;
        #pragma unroll
        for (int off = 32; off > 0; off >>= 1) ssq += __shfl_xor(ssq, off);
        float sc = 16.0f / fmaxf(sqrtf(ssq), 1e-12f);
        y.x *= sc; y.y *= sc; y.z *= sc; y.w *= sc;
        *(float4*)(out + (size_t)n * DD + lane * 4) = y;
        if (lane == 0) strel(&done[n], 1);
      }
      if (lane == 0) {
        int r = __hip_atomic_fetch_add(&ncnt[g], 1, __ATOMIC_ACQ_REL, __HIP_MEMORY_SCOPE_AGENT);
        if (r == 3) strel(&freec[slotr], (g >> 6) + 1);  // last N frees the ring slot
      }
    }
  }
}

extern "C" void kernel_launch(void* const* d_in, const int* in_sizes, int n_in,
                              void* d_out, int out_size, void* d_ws, size_t ws_size,
                              hipStream_t stream) {
  const int*   nin  = (const int*)  d_in[0];
  const int*   nty  = (const int*)  d_in[1];
  const float* root = (const float*)d_in[2];
  const float* slot = (const float*)d_in[3];
  const float* W1   = (const float*)d_in[4];
  const float* b1   = (const float*)d_in[5];
  const float* W2   = (const float*)d_in[6];
  const float* b2   = (const float*)d_in[7];
  float* out = (float*)d_out;     // fp32 [N, D] — used directly as the DAG buffer
  char* ws = (char*)d_ws;

  int maxb = 0;
  if (hipSuccess != hipOccupancyMaxActiveBlocksPerMultiprocessor(
          &maxb, (const void*)k_dag, 64, 0) || maxb <= 0)
    maxb = 8;
  if (maxb > 16) maxb = 16;       // conservative residency clamp (1-wave wg/CU)
  int G = maxb * 256;
  if (G > 4096) G = 4096;
  if (G < 256)  G = 256;

  k_sched_a<<<dim3(1), dim3(1024), 0, stream>>>(nin, root, ws, out);
  k_sched_b<<<dim3(1), dim3(1024), 0, stream>>>(nty, ws);
  k_dag<<<dim3(G), dim3(64), 0, stream>>>(nin, nty, slot, W1, b1, W2, b2, ws, out, G);
}

// Round 3
// 6954.328 us; speedup vs baseline: 1.7486x; 1.7486x over previous
//
#include <hip/hip_runtime.h>
#include <math.h>

#define NN     16384
#define DD     256
#define HH     1024
#define NROOTS 64
#define OUTST  96          // 32 trunk + 64 roots
#define TENC   33          // 32 trunk encoders + 1 output encoder
#define MAXL   256
#define NBINS  (MAXL*TENC) // 8448
#define GCAP   4096
#define RSLOTS 128         // ring of group slots
#define TPG    25          // tasks per group: 16 A + 8 B + 1 N

// ---- workspace byte offsets (ws[0..63] = hdr) ----
#define OFF_H      256u
#define OFF_YP     (OFF_H      + (unsigned)RSLOTS*16*HH*4u)   // h ring (8MB)
#define OFF_ORD    (OFF_YP     + (unsigned)RSLOTS*2*16*DD*4u) // y-partial ring (4MB)
#define OFF_META   (OFF_ORD    + (unsigned)NN*4u)
#define OFF_HC     (OFF_META   + (unsigned)GCAP*8u)
#define OFF_BC     (OFF_HC     + (unsigned)GCAP*4u)
#define OFF_FREE   (OFF_BC     + (unsigned)GCAP*4u)
#define OFF_LVLREM (OFF_FREE   + 512u)
#define OFF_WM     (OFF_LVLREM + (unsigned)MAXL*4u)
#define OFF_LVL    (OFF_WM     + 256u)
// end ~ 12.8 MB

__device__ __forceinline__ int ldrlx(int* p) {
  return __hip_atomic_load(p, __ATOMIC_RELAXED, __HIP_MEMORY_SCOPE_AGENT);
}
__device__ __forceinline__ void strel(int* p, int v) {
  __hip_atomic_store(p, v, __ATOMIC_RELEASE, __HIP_MEMORY_SCOPE_AGENT);
}
__device__ __forceinline__ void addrel(int* p) {
  __hip_atomic_fetch_add(p, 1, __ATOMIC_RELEASE, __HIP_MEMORY_SCOPE_AGENT);
}
__device__ __forceinline__ void acqfence() {
  __builtin_amdgcn_fence(__ATOMIC_ACQUIRE, "agent");
}
// single-thread spin with sleep backoff (callers park other threads at a barrier)
__device__ __forceinline__ void spin_ge(int* p, int target) {
  int it = 0;
  while (ldrlx(p) < target) {
    if (it < 4)       __builtin_amdgcn_s_sleep(2);
    else if (it < 32) __builtin_amdgcn_s_sleep(8);
    else              __builtin_amdgcn_s_sleep(32);
    if (++it > 3000000) break;   // hang fuse
  }
}

// =============== kernel 1a: levels + inits + roots ===============
__global__ __launch_bounds__(1024) void k_sched_a(
    const int* __restrict__ nin, const float* __restrict__ root,
    char* __restrict__ ws, float* __restrict__ out)
{
  __shared__ unsigned short lvl[NN];
  __shared__ int flag;
  int tid = threadIdx.x;
  for (int n = tid; n < NN; n += 1024) lvl[n] = 0;
  __syncthreads();
  for (int c = 0; c < 16; ++c) {
    int n = (c << 10) + tid;
    int p0 = nin[2*n], p1 = nin[2*n+1];
    bool live = (n >= NROOTS);
    while (true) {
      if (tid == 0) flag = 0;
      __syncthreads();
      if (live) {
        int nl = 1 + max((int)lvl[p0], (int)lvl[p1]);
        if (nl > (int)lvl[n]) { lvl[n] = (unsigned short)nl; flag = 1; }
      }
      __syncthreads();
      int f = flag;
      __syncthreads();
      if (!f) break;
    }
  }
  unsigned short* lvlg = (unsigned short*)(ws + OFF_LVL);
  for (int n = tid; n < NN; n += 1024) lvlg[n] = lvl[n];
  int* hc = (int*)(ws + OFF_HC); int* bc = (int*)(ws + OFF_BC);
  for (int i = tid; i < GCAP; i += 1024) { hc[i] = 0; bc[i] = 0; }
  int* fr = (int*)(ws + OFF_FREE);
  if (tid < RSLOTS) fr[tid] = 0;
  if (tid == 0) *(int*)(ws + OFF_WM) = 0;   // levels <= 0 (roots) complete
  for (int i = tid; i < NROOTS*DD; i += 1024) out[i] = root[i];
}

// =============== kernel 1b: counting sort by (level,type) + metadata ===============
__global__ __launch_bounds__(1024) void k_sched_b(
    const int* __restrict__ nty, char* __restrict__ ws)
{
  __shared__ int hist[NBINS];
  __shared__ int wsum[16], wsum2[16];
  const unsigned short* lvl = (const unsigned short*)(ws + OFF_LVL);
  int*  order  = (int*)(ws + OFF_ORD);
  int2* meta   = (int2*)(ws + OFF_META);
  int*  lvlrem = (int*)(ws + OFF_LVLREM);
  int*  hdr    = (int*)ws;
  int tid = threadIdx.x;
  for (int i = tid; i < NBINS; i += 1024) hist[i] = 0;
  __syncthreads();
  for (int n = NROOTS + tid; n < NN; n += 1024) {
    int ty = nty[n];
    int pi = (ty >= OUTST) ? 32 : ty;
    int key = min((int)lvl[n] - 1, MAXL - 1) * TENC + pi;
    atomicAdd(&hist[key], 1);
  }
  __syncthreads();
  // per-level node counts (level = tid+1)
  if (tid < MAXL) {
    int s2 = 0;
    for (int pi = 0; pi < TENC; ++pi) s2 += hist[tid*TENC + pi];
    lvlrem[tid] = s2;
  }
  __syncthreads();
  int base = tid * 9;
  int v[9]; int s = 0, gs = 0;
  #pragma unroll
  for (int j = 0; j < 9; ++j) {
    int idx = base + j;
    int cv = (idx < NBINS) ? hist[idx] : 0;
    v[j] = cv; s += cv; gs += (cv + 15) >> 4;
  }
  int lane = tid & 63, wid = tid >> 6;
  int xs = s, xg = gs;
  for (int off = 1; off < 64; off <<= 1) {
    int ys = __shfl_up(xs, off); int yg = __shfl_up(xg, off);
    if (lane >= off) { xs += ys; xg += yg; }
  }
  if (lane == 63) { wsum[wid] = xs; wsum2[wid] = xg; }
  __syncthreads();
  if (tid == 0) {
    int a = 0, b = 0;
    for (int w = 0; w < 16; ++w) {
      int t1 = wsum[w];  wsum[w]  = a; a += t1;
      int t2 = wsum2[w]; wsum2[w] = b; b += t2;
    }
    hdr[0] = b;            // num groups
    hdr[1] = b * TPG;      // total tasks
  }
  __syncthreads();
  int run  = (xs - s)  + wsum[wid];
  int grun = (xg - gs) + wsum2[wid];
  #pragma unroll
  for (int j = 0; j < 9; ++j) {
    int idx = base + j;
    if (idx < NBINS) {
      int cv = v[j];
      int pi = idx % TENC;
      int L  = idx / TENC + 1;
      hist[idx] = run;  // becomes running scatter offset
      int ng = (cv + 15) >> 4;
      for (int sg = 0; sg < ng; ++sg) {
        int m = min(16, cv - 16*sg);
        meta[grun + sg] = make_int2(run + 16*sg, m | (pi << 8) | (L << 16));
      }
      run += cv; grun += ng;
    }
  }
  __syncthreads();
  for (int n = NROOTS + tid; n < NN; n += 1024) {
    int ty = nty[n];
    int pi = (ty >= OUTST) ? 32 : ty;
    int key = min((int)lvl[n] - 1, MAXL - 1) * TENC + pi;
    int pos = atomicAdd(&hist[key], 1);
    order[pos] = n;
  }
}

// =============== kernel 2: persistent event-driven DAG executor ===============
// 25 tasks per 16-node group g (global topo order), 256-thread (4-wave) blocks:
//   sub 0..15 : A — layer1 64-col tile; 4 waves split K=512; LDS reduce; GELU -> h ring
//   sub 16..23: B — layer2 (col-tile, K-half); 4 waves split K=512; LDS reduce -> ypart
//   sub 24    : N — sum 2 K-halves + bias, normalize, write out, level accounting
__global__ __launch_bounds__(256, 4) void k_dag(
    const int* __restrict__ nin, const int* __restrict__ nty,
    const float* __restrict__ slotemb,
    const float* __restrict__ W1, const float* __restrict__ b1,
    const float* __restrict__ W2, const float* __restrict__ b2,
    char* __restrict__ ws, float* __restrict__ out, int G)
{
  int*   hdr   = (int*)ws;
  float* hring = (float*)(ws + OFF_H);
  float* ypart = (float*)(ws + OFF_YP);
  const int*  order = (const int*)(ws + OFF_ORD);
  const int2* meta  = (const int2*)(ws + OFF_META);
  int* hcnt   = (int*)(ws + OFF_HC);
  int* bcnt   = (int*)(ws + OFF_BC);
  int* freec  = (int*)(ws + OFF_FREE);
  int* lvlrem = (int*)(ws + OFF_LVLREM);
  int* wm     = (int*)(ws + OFF_WM);

  __shared__ float ldsf[8192];          // 32KB: per-wave stage / partial overlay
  float4* lds4 = (float4*)ldsf;
  __shared__ int sm_n[16], sm_p0[16], sm_p1[16], sm_ty[16];

  const int total = hdr[1];
  const int tid  = threadIdx.x;
  const int lane = tid & 63;
  const int wv   = tid >> 6;

  for (int t = blockIdx.x; t < total; t += G) {
    int g = t / TPG;
    int sub = t - g * TPG;
    int2 mt = meta[g];
    int pos0 = mt.x;
    int M    = mt.y & 0xff;
    int pidx = (mt.y >> 8) & 0xff;
    int L    = mt.y >> 16;
    int slotr = g & (RSLOTS - 1);
    int epoch = g >> 7;               // g / RSLOTS

    if (sub < 16) {
      // ---------------- A: layer 1 (64 cols, K split 4x128) ----------------
      if (tid == 0) {
        spin_ge(wm, L - 1);           // all parents (levels < L) complete
        spin_ge(&freec[slotr], epoch);// ring slot reusable
        acqfence();
      }
      __syncthreads();
      acqfence();
      if (tid < 16) {
        int n = order[pos0 + min(tid, M - 1)];
        sm_n[tid] = n; sm_p0[tid] = nin[2*n]; sm_p1[tid] = nin[2*n+1]; sm_ty[tid] = nty[n];
      }
      __syncthreads();
      // stage: wave wv covers k in [wv*128, wv*128+128)
      int half = wv >> 1;             // 0 -> e0 (parent0), 1 -> e1 (parent1/slot)
      int cb = (wv & 1) * 128;        // column base within that 256-wide half
      #pragma unroll
      for (int i = 0; i < 8; ++i) {
        int idx = i * 64 + lane;
        int m = idx >> 5, k4 = idx & 31;
        const float* src;
        if (half == 0)            src = out + (size_t)sm_p0[m] * DD;
        else if (pidx == 32)      src = slotemb + (size_t)(sm_ty[m] - OUTST) * DD;
        else                      src = out + (size_t)sm_p1[m] * DD;
        lds4[wv*512 + m*32 + k4] = *(const float4*)(src + cb + k4*4);
      }
      // gemv: col C = sub*64+lane, rows k = wv*128 + 4*kq + j
      int C = (sub << 6) + lane;
      float acc[16];
      #pragma unroll
      for (int m = 0; m < 16; ++m) acc[m] = 0.0f;
      const float* wp = W1 + (size_t)pidx * (2*DD*HH) + (size_t)(wv*128) * HH + C;
      #pragma unroll 4
      for (int kq = 0; kq < 32; ++kq) {
        const float* wr = wp + (size_t)kq * 4 * HH;
        float w0 = wr[0], w1 = wr[HH], w2 = wr[2*HH], w3 = wr[3*HH];
        #pragma unroll
        for (int m = 0; m < 16; ++m) {
          float4 x = lds4[wv*512 + m*32 + kq];
          acc[m] = fmaf(x.x, w0, acc[m]);
          acc[m] = fmaf(x.y, w1, acc[m]);
          acc[m] = fmaf(x.z, w2, acc[m]);
          acc[m] = fmaf(x.w, w3, acc[m]);
        }
      }
      // per-wave partials (overlay own stage region), then combine
      #pragma unroll
      for (int m = 0; m < 16; ++m) ldsf[wv*2048 + m*64 + lane] = acc[m];
      __syncthreads();
      float bb = b1[pidx * HH + C];
      #pragma unroll
      for (int j = 0; j < 4; ++j) {
        int m = wv * 4 + j;
        float v = ldsf[m*64+lane] + ldsf[2048 + m*64+lane]
                + ldsf[4096 + m*64+lane] + ldsf[6144 + m*64+lane] + bb;
        v = 0.5f * v * (1.0f + erff(v * 0.70710678118654752f));   // exact GELU
        hring[((size_t)slotr * 16 + m) * HH + C] = v;
      }
      __syncthreads();                 // drains all waves' h stores (vmcnt 0 at barrier)
      if (tid == 0) addrel(&hcnt[g]);

    } else if (sub < 24) {
      // ---------------- B: layer 2 (64-col y tile, K-half; 4 waves x 128) ----------------
      int bi = sub - 16;
      int ct = bi >> 1;               // y col tile (0..3)
      int kh = bi & 1;                // K half (0..1) of 1024
      if (tid == 0) { spin_ge(&hcnt[g], 16); acqfence(); }
      __syncthreads();
      acqfence();
      int C = (ct << 6) + lane;
      float acc[16];
      #pragma unroll
      for (int m = 0; m < 16; ++m) acc[m] = 0.0f;
      int kbw = kh * 512 + wv * 128;  // this wave's k base in h
      const float* wpb = W2 + (size_t)pidx * (HH*DD) + (size_t)kbw * DD + C;
      #pragma unroll
      for (int cs = 0; cs < 2; ++cs) {
        int kb2 = kbw + cs * 64;
        #pragma unroll
        for (int i = 0; i < 4; ++i) {
          int idx = i * 64 + lane;
          int m = idx >> 4, k4 = idx & 15;
          lds4[wv*512 + m*16 + k4] =
              *(const float4*)(hring + ((size_t)slotr*16 + m)*HH + kb2 + k4*4);
        }
        #pragma unroll 4
        for (int kq = 0; kq < 16; ++kq) {
          const float* wr = wpb + (size_t)(cs*64 + kq*4) * DD;
          float w0 = wr[0], w1 = wr[DD], w2 = wr[2*DD], w3 = wr[3*DD];
          #pragma unroll
          for (int m = 0; m < 16; ++m) {
            float4 x = lds4[wv*512 + m*16 + kq];
            acc[m] = fmaf(x.x, w0, acc[m]);
            acc[m] = fmaf(x.y, w1, acc[m]);
            acc[m] = fmaf(x.z, w2, acc[m]);
            acc[m] = fmaf(x.w, w3, acc[m]);
          }
        }
      }
      #pragma unroll
      for (int m = 0; m < 16; ++m) ldsf[wv*2048 + m*64 + lane] = acc[m];
      __syncthreads();
      #pragma unroll
      for (int j = 0; j < 4; ++j) {
        int m = wv * 4 + j;
        float v = ldsf[m*64+lane] + ldsf[2048 + m*64+lane]
                + ldsf[4096 + m*64+lane] + ldsf[6144 + m*64+lane];
        ypart[(((size_t)slotr*2 + kh) * 16 + m) * DD + C] = v;
      }
      __syncthreads();
      if (tid == 0) addrel(&bcnt[g]);

    } else {
      // ---------------- N: combine halves + bias + normalize + write ----------------
      if (tid == 0) { spin_ge(&bcnt[g], 8); acqfence(); }
      __syncthreads();
      acqfence();
      if (tid < 16) sm_n[tid] = order[pos0 + min(tid, M - 1)];
      __syncthreads();
      const float4* b2v = (const float4*)(b2 + pidx * DD);
      #pragma unroll
      for (int j = 0; j < 4; ++j) {
        int m = wv * 4 + j;
        if (m < M) {
          int n = sm_n[m];
          float4 y = b2v[lane];
          float4 a0 = ((const float4*)(ypart + (((size_t)slotr*2 + 0)*16 + m)*DD))[lane];
          float4 a1 = ((const float4*)(ypart + (((size_t)slotr*2 + 1)*16 + m)*DD))[lane];
          y.x += a0.x + a1.x; y.y += a0.y + a1.y;
          y.z += a0.z + a1.z; y.w += a0.w + a1.w;
          float ssq = y.x*y.x + y.y*y.y + y.z*y.z + y.w*y.w;
          #pragma unroll
          for (int off = 32; off > 0; off >>= 1) ssq += __shfl_xor(ssq, off);
          float sc = 16.0f / fmaxf(sqrtf(ssq), 1e-12f);
          y.x *= sc; y.y *= sc; y.z *= sc; y.w *= sc;
          *(float4*)(out + (size_t)n * DD + lane * 4) = y;
        }
      }
      __syncthreads();                 // all rows drained to memory
      if (tid == 0) {
        int old = __hip_atomic_fetch_add(&lvlrem[L-1], -M, __ATOMIC_ACQ_REL,
                                         __HIP_MEMORY_SCOPE_AGENT);
        if (old == M) strel(wm, L);    // last group of this level -> advance watermark
        strel(&freec[slotr], epoch + 1);
      }
    }
  }
}

extern "C" void kernel_launch(void* const* d_in, const int* in_sizes, int n_in,
                              void* d_out, int out_size, void* d_ws, size_t ws_size,
                              hipStream_t stream) {
  const int*   nin  = (const int*)  d_in[0];
  const int*   nty  = (const int*)  d_in[1];
  const float* root = (const float*)d_in[2];
  const float* slot = (const float*)d_in[3];
  const float* W1   = (const float*)d_in[4];
  const float* b1   = (const float*)d_in[5];
  const float* W2   = (const float*)d_in[6];
  const float* b2   = (const float*)d_in[7];
  float* out = (float*)d_out;     // fp32 [N, D] doubles as the DAG embedding buffer
  char* ws = (char*)d_ws;

  int maxb = 0;
  if (hipSuccess != hipOccupancyMaxActiveBlocksPerMultiprocessor(
          &maxb, (const void*)k_dag, 256, 0) || maxb <= 0)
    maxb = 4;
  int G = maxb * 256;             // guaranteed-resident persistent grid
  if (G > 2048) G = 2048;
  if (G < 256)  G = 256;

  k_sched_a<<<dim3(1), dim3(1024), 0, stream>>>(nin, root, ws, out);
  k_sched_b<<<dim3(1), dim3(1024), 0, stream>>>(nty, ws);
  k_dag<<<dim3(G), dim3(256), 0, stream>>>(nin, nty, slot, W1, b1, W2, b2, ws, out, G);
}